// Round 3
// baseline (679.576 us; speedup 1.0000x reference)
//
#include <hip/hip_runtime.h>
#include <hip/hip_bf16.h>

// GCN layer: N=100000, E=1600000, IN=256, OUT=32, fp32.
// Bucketed-LDS pipeline (no float atomics, no CSR scatter):
//   1) degree_kernel: cnt_out[src]++, cnt_in[dst]++, per-block bucket hist
//   2) gemm_kernel:   h = (feat * out_deg^-0.5) @ W
//   3) bucket_scan:   exclusive scan of 256 bucket counts -> base/cursor
//   4) partition_kernel: block-local LDS counting sort -> pairs[] grouped by
//      dst-bucket (packed u32: src[16:0] | dstlow[25:17]); coalesced flush
//   5) bucket_agg_kernel: 1 block/bucket, 64KB LDS acc[512][32] (bank=lane),
//      ds_add_f32 accumulate; fused in_deg^-0.5 + bias + relu epilogue
// Fallback: float-atomic aggregate if ws too small or N >= 2^17.

#define IN_F 256
#define OUT_F 32
#define ROWS 64
#define KT 64
#define KT_PAD (KT + 4)

#define BSHIFT 9              // 512 nodes per bucket
#define BNODES 512
#define NBMAX 256
#define DEG_EPB 4096          // edges per degree block
#define PB_EDGES 8192         // edges per partition block

__global__ __launch_bounds__(256) void degree_kernel(
    const int* __restrict__ src, const int* __restrict__ dst,
    int* __restrict__ cnt_out, int* __restrict__ cnt_in,
    int* __restrict__ bucket_cnt, int E) {
  __shared__ int hist[NBMAX];
  int tid = threadIdx.x;
  hist[tid] = 0;
  __syncthreads();
  int base = blockIdx.x * DEG_EPB + tid * 16;
  if (base + 16 <= E) {
#pragma unroll
    for (int i = 0; i < 4; ++i) {
      int4 s4 = ((const int4*)(src + base))[i];
      int4 d4 = ((const int4*)(dst + base))[i];
      int ss[4] = {s4.x, s4.y, s4.z, s4.w};
      int dd[4] = {d4.x, d4.y, d4.z, d4.w};
#pragma unroll
      for (int k = 0; k < 4; ++k) {
        atomicAdd(cnt_out + ss[k], 1);
        atomicAdd(cnt_in + dd[k], 1);
        atomicAdd(&hist[dd[k] >> BSHIFT], 1);
      }
    }
  } else {
    for (int j = 0; j < 16; ++j) {
      int e = base + j;
      if (e < E) {
        int s = src[e], d = dst[e];
        atomicAdd(cnt_out + s, 1);
        atomicAdd(cnt_in + d, 1);
        atomicAdd(&hist[d >> BSHIFT], 1);
      }
    }
  }
  __syncthreads();
  if (hist[tid]) atomicAdd(bucket_cnt + tid, hist[tid]);
}

// h[n][o] = sum_k feat[n][k] * out_deg[n]^-0.5 * W[k][o]
__global__ __launch_bounds__(256, 3) void gemm_kernel(
    const float* __restrict__ feat, const float* __restrict__ W,
    const int* __restrict__ cnt_out, float* __restrict__ h, int N) {
  __shared__ float sW[IN_F * OUT_F];
  __shared__ float sF[ROWS * KT_PAD];

  int tid = threadIdx.x;
  {
    const float4* W4 = (const float4*)W;
    float4* sW4 = (float4*)sW;
#pragma unroll
    for (int i = 0; i < 8; ++i) sW4[tid + i * 256] = W4[tid + i * 256];
  }

  int row0 = blockIdx.x * ROWS;
  int rg = tid >> 3;
  int cg = (tid & 7) * 4;
  float4 acc0 = {0.f, 0.f, 0.f, 0.f};
  float4 acc1 = {0.f, 0.f, 0.f, 0.f};

  for (int kt = 0; kt < IN_F; kt += KT) {
    __syncthreads();
#pragma unroll
    for (int i = 0; i < 4; ++i) {
      int idx = tid + i * 256;
      int r = idx >> 4;
      int kk = (idx & 15) * 4;
      int gr = row0 + r;
      float4 v = {0.f, 0.f, 0.f, 0.f};
      if (gr < N) {
        float dg = (float)cnt_out[gr];
        float s = dg < 1.f ? 1.f : rsqrtf(dg);
        v = *(const float4*)(feat + (size_t)gr * IN_F + kt + kk);
        v.x *= s; v.y *= s; v.z *= s; v.w *= s;
      }
      *(float4*)(sF + r * KT_PAD + kk) = v;
    }
    __syncthreads();

    const float* fr0 = sF + rg * KT_PAD;
    const float* fr1 = sF + (rg + 32) * KT_PAD;
#pragma unroll
    for (int k4 = 0; k4 < KT; k4 += 4) {
      float4 a0 = *(const float4*)(fr0 + k4);
      float4 a1 = *(const float4*)(fr1 + k4);
#pragma unroll
      for (int j = 0; j < 4; ++j) {
        float4 w = *(const float4*)(sW + (kt + k4 + j) * OUT_F + cg);
        float aj0 = (j == 0) ? a0.x : (j == 1) ? a0.y : (j == 2) ? a0.z : a0.w;
        float aj1 = (j == 0) ? a1.x : (j == 1) ? a1.y : (j == 2) ? a1.z : a1.w;
        acc0.x += aj0 * w.x; acc0.y += aj0 * w.y;
        acc0.z += aj0 * w.z; acc0.w += aj0 * w.w;
        acc1.x += aj1 * w.x; acc1.y += aj1 * w.y;
        acc1.z += aj1 * w.z; acc1.w += aj1 * w.w;
      }
    }
  }

  int g0 = row0 + rg, g1 = row0 + rg + 32;
  if (g0 < N) *(float4*)(h + (size_t)g0 * OUT_F + cg) = acc0;
  if (g1 < N) *(float4*)(h + (size_t)g1 * OUT_F + cg) = acc1;
}

__global__ __launch_bounds__(256) void bucket_scan_kernel(
    const int* __restrict__ bucket_cnt, int* __restrict__ bucket_base,
    int* __restrict__ bucket_cursor) {
  __shared__ int wsum[4];
  int tid = threadIdx.x;
  int v = bucket_cnt[tid];
  int x = v;
#pragma unroll
  for (int d = 1; d < 64; d <<= 1) {
    int y = __shfl_up(x, d, 64);
    if ((tid & 63) >= d) x += y;
  }
  if ((tid & 63) == 63) wsum[tid >> 6] = x;
  __syncthreads();
  int off = 0;
#pragma unroll
  for (int w = 0; w < 4; ++w)
    if (w < (tid >> 6)) off += wsum[w];
  int excl = off + x - v;
  bucket_base[tid] = excl;
  bucket_cursor[tid] = excl;
}

// Block-local counting sort of PB_EDGES edges into dst-buckets, then
// coalesced segment flush to pairs[] at globally reserved offsets.
__global__ __launch_bounds__(1024) void partition_kernel(
    const int* __restrict__ src, const int* __restrict__ dst,
    int* __restrict__ bucket_cursor, unsigned* __restrict__ pairs, int E) {
  __shared__ unsigned sbuf[PB_EDGES];   // 32 KB
  __shared__ int hist[NBMAX];
  __shared__ int lbase[NBMAX + 1];
  __shared__ int gbase[NBMAX];
  __shared__ int wsum[16];

  int tid = threadIdx.x;
  if (tid < NBMAX) hist[tid] = 0;
  __syncthreads();

  int e0 = blockIdx.x * PB_EDGES + tid * 8;
  int myb[8], myslot[8];
  unsigned mypk[8];
  if (e0 + 8 <= E) {
    int4 s0 = ((const int4*)(src + e0))[0];
    int4 s1 = ((const int4*)(src + e0))[1];
    int4 d0 = ((const int4*)(dst + e0))[0];
    int4 d1 = ((const int4*)(dst + e0))[1];
    int ss[8] = {s0.x, s0.y, s0.z, s0.w, s1.x, s1.y, s1.z, s1.w};
    int dd[8] = {d0.x, d0.y, d0.z, d0.w, d1.x, d1.y, d1.z, d1.w};
#pragma unroll
    for (int j = 0; j < 8; ++j) {
      int b = dd[j] >> BSHIFT;
      myb[j] = b;
      mypk[j] = (unsigned)ss[j] | ((unsigned)(dd[j] & (BNODES - 1)) << 17);
      myslot[j] = atomicAdd(&hist[b], 1);
    }
  } else {
#pragma unroll
    for (int j = 0; j < 8; ++j) {
      int e = e0 + j;
      if (e < E) {
        int s = src[e], d = dst[e];
        int b = d >> BSHIFT;
        myb[j] = b;
        mypk[j] = (unsigned)s | ((unsigned)(d & (BNODES - 1)) << 17);
        myslot[j] = atomicAdd(&hist[b], 1);
      } else {
        myb[j] = -1;
      }
    }
  }
  __syncthreads();

  // exclusive scan of hist[0..255] -> lbase (all threads run the shfl code)
  {
    int v = (tid < NBMAX) ? hist[tid] : 0;
    int x = v;
#pragma unroll
    for (int d = 1; d < 64; d <<= 1) {
      int y = __shfl_up(x, d, 64);
      if ((tid & 63) >= d) x += y;
    }
    if ((tid & 63) == 63) wsum[tid >> 6] = x;
    __syncthreads();
    int off = 0;
#pragma unroll
    for (int w = 0; w < 4; ++w)
      if (w < (tid >> 6)) off += wsum[w];
    if (tid < NBMAX) {
      lbase[tid] = off + x - v;
      if (tid == NBMAX - 1) lbase[NBMAX] = off + x;
      // reserve global space for this block's segment of bucket `tid`
      gbase[tid] = v ? atomicAdd(&bucket_cursor[tid], v) : 0;
    }
  }
  __syncthreads();

  // place packed edges into LDS, sorted by bucket
#pragma unroll
  for (int j = 0; j < 8; ++j)
    if (myb[j] >= 0) sbuf[lbase[myb[j]] + myslot[j]] = mypk[j];
  __syncthreads();

  // coalesced-ish copyout: thread t handles sbuf[t*8 .. t*8+7]
  int total = lbase[NBMAX];
  int idx = tid * 8;
  if (idx < total) {
    // binary search bucket of idx
    int lo = 0, hi = NBMAX;
    while (hi - lo > 1) {
      int mid = (lo + hi) >> 1;
      if (lbase[mid] <= idx) lo = mid; else hi = mid;
    }
    int b = lo;
#pragma unroll
    for (int j = 0; j < 8; ++j, ++idx) {
      if (idx >= total) break;
      while (idx >= lbase[b + 1]) ++b;
      pairs[gbase[b] + (idx - lbase[b])] = sbuf[idx];
    }
  }
}

// One block per bucket: LDS accumulate h rows, fused scale+bias+relu epilogue.
__global__ __launch_bounds__(512) void bucket_agg_kernel(
    const unsigned* __restrict__ pairs, const int* __restrict__ bucket_base,
    const int* __restrict__ bucket_cursor, const float* __restrict__ h,
    const int* __restrict__ cnt_in, const float* __restrict__ bias,
    float* __restrict__ out, int N) {
  __shared__ float acc[BNODES * OUT_F];   // 64 KB, bank = lane
  int tid = threadIdx.x;
  {
    float4 z = {0.f, 0.f, 0.f, 0.f};
    float4* a4 = (float4*)acc;
#pragma unroll
    for (int i = 0; i < 8; ++i) a4[tid + i * 512] = z;
  }
  __syncthreads();

  int b = blockIdx.x;
  int start = bucket_base[b];
  int end = bucket_cursor[b];
  int lane = tid & 31;
  int eg = tid >> 5;   // 16 edge slots

  for (int j = start + eg; j < end; j += 64) {
    unsigned pk0 = pairs[j];
    bool v1 = (j + 16) < end, v2 = (j + 32) < end, v3 = (j + 48) < end;
    unsigned pk1 = v1 ? pairs[j + 16] : pk0;
    unsigned pk2 = v2 ? pairs[j + 32] : pk0;
    unsigned pk3 = v3 ? pairs[j + 48] : pk0;
    float f0 = h[(pk0 & 0x1FFFF) * OUT_F + lane];
    float f1 = h[(pk1 & 0x1FFFF) * OUT_F + lane];
    float f2 = h[(pk2 & 0x1FFFF) * OUT_F + lane];
    float f3 = h[(pk3 & 0x1FFFF) * OUT_F + lane];
    atomicAdd(&acc[(pk0 >> 17) * OUT_F + lane], f0);
    if (v1) atomicAdd(&acc[(pk1 >> 17) * OUT_F + lane], f1);
    if (v2) atomicAdd(&acc[(pk2 >> 17) * OUT_F + lane], f2);
    if (v3) atomicAdd(&acc[(pk3 >> 17) * OUT_F + lane], f3);
  }
  __syncthreads();

  int node0 = b << BSHIFT;
  for (int r = eg; r < BNODES; r += 16) {
    int node = node0 + r;
    if (node < N) {
      float dg = (float)cnt_in[node];
      float sc = dg < 1.f ? 1.f : rsqrtf(dg);
      float v = fmaf(acc[r * OUT_F + lane], sc, bias[lane]);
      out[(size_t)node * OUT_F + lane] = fmaxf(v, 0.f);
    }
  }
}

// ---- fallback (float-atomic) path ----
__global__ __launch_bounds__(256) void aggregate_kernel(
    const int* __restrict__ src, const int* __restrict__ dst,
    const float* __restrict__ h, float* __restrict__ out, int E) {
  int lane = threadIdx.x & 31;
  int e = (blockIdx.x * 256 + threadIdx.x) >> 5;
  if (e >= E) return;
  float v = h[(size_t)src[e] * OUT_F + lane];
  unsafeAtomicAdd(out + (size_t)dst[e] * OUT_F + lane, v);
}

__global__ __launch_bounds__(256) void finalize_kernel(
    float* __restrict__ out, const int* __restrict__ cnt_in,
    const float* __restrict__ bias, int N) {
  int idx = blockIdx.x * 256 + threadIdx.x;
  if (idx >= N * 8) return;
  int n = idx >> 3;
  int o = (idx & 7) * 4;
  float dg = (float)cnt_in[n];
  float s = dg < 1.f ? 1.f : rsqrtf(dg);
  float4 bv = *(const float4*)(bias + o);
  float4 v = ((const float4*)out)[idx];
  v.x = fmaxf(fmaf(v.x, s, bv.x), 0.f);
  v.y = fmaxf(fmaf(v.y, s, bv.y), 0.f);
  v.z = fmaxf(fmaf(v.z, s, bv.z), 0.f);
  v.w = fmaxf(fmaf(v.w, s, bv.w), 0.f);
  ((float4*)out)[idx] = v;
}

extern "C" void kernel_launch(void* const* d_in, const int* in_sizes, int n_in,
                              void* d_out, int out_size, void* d_ws, size_t ws_size,
                              hipStream_t stream) {
  const float* feat = (const float*)d_in[0];
  const int* src = (const int*)d_in[1];
  const int* dst = (const int*)d_in[2];
  const float* weight = (const float*)d_in[3];
  const float* bias = (const float*)d_in[4];
  float* out = (float*)d_out;

  int N = in_sizes[0] / IN_F;
  int E = in_sizes[1];
  int nb = (N + BNODES - 1) >> BSHIFT;

  float* h = (float*)d_ws;                        // N*32 floats
  int* cnt_out = (int*)(h + (size_t)N * OUT_F);   // N
  int* cnt_in = cnt_out + N;                      // N
  int* bucket_cnt = cnt_in + N;                   // 256
  int* bucket_base = bucket_cnt + NBMAX;          // 257
  int* bucket_cursor = bucket_base + NBMAX + 1;   // 256
  unsigned* pairs = (unsigned*)(bucket_cursor + NBMAX);  // E

  size_t need = ((size_t)N * OUT_F + 2 * (size_t)N + (3 * NBMAX + 1) + (size_t)E) * 4;
  bool fast = (ws_size >= need) && (N <= (1 << 17)) && (nb <= NBMAX);

  if (fast) {
    hipMemsetAsync(cnt_out, 0, ((size_t)2 * N + NBMAX) * sizeof(int), stream);
    degree_kernel<<<(E + DEG_EPB - 1) / DEG_EPB, 256, 0, stream>>>(
        src, dst, cnt_out, cnt_in, bucket_cnt, E);
    gemm_kernel<<<(N + ROWS - 1) / ROWS, 256, 0, stream>>>(feat, weight, cnt_out, h, N);
    bucket_scan_kernel<<<1, 256, 0, stream>>>(bucket_cnt, bucket_base, bucket_cursor);
    partition_kernel<<<(E + PB_EDGES - 1) / PB_EDGES, 1024, 0, stream>>>(
        src, dst, bucket_cursor, pairs, E);
    bucket_agg_kernel<<<nb, 512, 0, stream>>>(
        pairs, bucket_base, bucket_cursor, h, cnt_in, bias, out, N);
  } else {
    hipMemsetAsync(cnt_out, 0, (size_t)2 * N * sizeof(int), stream);
    hipMemsetAsync(out, 0, (size_t)N * OUT_F * sizeof(float), stream);
    degree_kernel<<<(E + DEG_EPB - 1) / DEG_EPB, 256, 0, stream>>>(
        src, dst, cnt_out, cnt_in, bucket_cnt, E);
    gemm_kernel<<<(N + ROWS - 1) / ROWS, 256, 0, stream>>>(feat, weight, cnt_out, h, N);
    aggregate_kernel<<<(E + 7) / 8, 256, 0, stream>>>(src, dst, h, out, E);
    finalize_kernel<<<(N * 8 + 255) / 256, 256, 0, stream>>>(out, cnt_in, bias, N);
  }
}